// Round 1
// baseline (5330.259 us; speedup 1.0000x reference)
//
#include <hip/hip_runtime.h>
#include <math.h>

#define BB 32
#define TT 50
#define HH 1024
#define DD 512
#define VV 50257
#define G4H 4096

// ---------------------------------------------------------------------------
// Kernel A: xg[bt][n] = dot(emb[tok(bt)], W_ih[n,:]) + b_ih[n] + b_hh[n]
// M=1600 (bt), N=4096 (gate rows), K=512. 64x64 tile, BK=16, 4x4 per thread.
// tok(bt): t==0 -> 1 (BOS), else targets[b][t-1]
// ---------------------------------------------------------------------------
__global__ void xg_gemm(const int* __restrict__ targets,
                        const float* __restrict__ emb,
                        const float* __restrict__ W_ih,
                        const float* __restrict__ b_ih,
                        const float* __restrict__ b_hh,
                        float* __restrict__ xg) {
    __shared__ float As[16][65];
    __shared__ float Bs[16][65];
    const int m0 = blockIdx.y * 64;
    const int n0 = blockIdx.x * 64;
    const int tid = threadIdx.x;
    const int tx = tid & 15;        // n micro index
    const int ty = tid >> 4;        // m micro index
    const int lk = tx;              // load: k within tile
    const int lm = ty;              // load: row within tile (4 strided)

    const float* arow[4];
    const float* brow[4];
#pragma unroll
    for (int i = 0; i < 4; i++) {
        int bt = m0 + lm + i * 16;
        int b = bt / TT, t = bt % TT;
        int tok = (t == 0) ? 1 : targets[b * TT + (t - 1)];
        arow[i] = emb + (size_t)tok * DD;
        int n = n0 + lm + i * 16;
        brow[i] = W_ih + (size_t)n * DD;
    }

    float acc[4][4] = {};
    for (int k0 = 0; k0 < DD; k0 += 16) {
#pragma unroll
        for (int i = 0; i < 4; i++) As[lk][lm + i * 16] = arow[i][k0 + lk];
#pragma unroll
        for (int i = 0; i < 4; i++) Bs[lk][lm + i * 16] = brow[i][k0 + lk];
        __syncthreads();
#pragma unroll
        for (int k = 0; k < 16; k++) {
            float a[4], bb[4];
#pragma unroll
            for (int i = 0; i < 4; i++) a[i] = As[k][ty + i * 16];
#pragma unroll
            for (int j = 0; j < 4; j++) bb[j] = Bs[k][tx + j * 16];
#pragma unroll
            for (int i = 0; i < 4; i++)
#pragma unroll
                for (int j = 0; j < 4; j++) acc[i][j] += a[i] * bb[j];
        }
        __syncthreads();
    }
#pragma unroll
    for (int i = 0; i < 4; i++) {
        int m = m0 + ty + i * 16;
#pragma unroll
        for (int j = 0; j < 4; j++) {
            int n = n0 + tx + j * 16;
            xg[(size_t)m * G4H + n] = acc[i][j] + b_ih[n] + b_hh[n];
        }
    }
}

// ---------------------------------------------------------------------------
// Kernel B: one LSTM time step.
// Each block: 8 gate-indices n (of 1024) x all 32 batches. 256 threads:
// b = tid&31, jl = tid>>5. Each thread computes the 4 gate dots (i,f,g,o)
// of length 1024 against h_prev, then updates c and h.
// W_hh rows: gate gi row = gi*1024 + n. Read exactly once per step.
// ---------------------------------------------------------------------------
__global__ void lstm_step(const float* __restrict__ W_hh,
                          const float* __restrict__ xg,
                          const float* __restrict__ h_prev,
                          float* __restrict__ c_buf,
                          float* __restrict__ h_out,
                          float* __restrict__ hs_all,
                          int t) {
    __shared__ float h_s[32][65];
    __shared__ float w_s[32][65];
    const int tid = threadIdx.x;
    const int b = tid & 31;
    const int jl = tid >> 5;            // 0..7
    const int n0 = blockIdx.x * 8;
    const int n = n0 + jl;

    float acc[4] = {0.f, 0.f, 0.f, 0.f};
    for (int k0 = 0; k0 < HH; k0 += 64) {
#pragma unroll
        for (int i = 0; i < 8; i++) {
            int e = tid + i * 256;       // 0..2047
            int r = e >> 6;              // 0..31
            int kk = e & 63;
            h_s[r][kk] = h_prev[r * HH + k0 + kk];
            int gi = r >> 3, jj = r & 7;
            w_s[r][kk] = W_hh[(size_t)(gi * HH + n0 + jj) * HH + k0 + kk];
        }
        __syncthreads();
#pragma unroll
        for (int k = 0; k < 64; k++) {
            float hv = h_s[b][k];
            acc[0] += hv * w_s[jl][k];
            acc[1] += hv * w_s[8 + jl][k];
            acc[2] += hv * w_s[16 + jl][k];
            acc[3] += hv * w_s[24 + jl][k];
        }
        __syncthreads();
    }

    const int bt = b * TT + t;
    float gi_ = acc[0] + xg[(size_t)bt * G4H + n];
    float gf_ = acc[1] + xg[(size_t)bt * G4H + HH + n];
    float gg_ = acc[2] + xg[(size_t)bt * G4H + 2 * HH + n];
    float go_ = acc[3] + xg[(size_t)bt * G4H + 3 * HH + n];

    float i_ = 1.f / (1.f + expf(-gi_));
    float f_ = 1.f / (1.f + expf(-gf_));
    float g_ = tanhf(gg_);
    float o_ = 1.f / (1.f + expf(-go_));

    float c_old = (t == 0) ? 0.f : c_buf[b * HH + n];
    float c_new = f_ * c_old + i_ * g_;
    float h_new = o_ * tanhf(c_new);

    c_buf[b * HH + n] = c_new;
    h_out[b * HH + n] = h_new;
    hs_all[(size_t)bt * HH + n] = h_new;
}

// ---------------------------------------------------------------------------
// Kernel C: logits[bt][v] = dot(hs[bt,:], W_proj[v,:]) + b_proj[v]
// M=1600, N=50257, K=1024. Same 64x64 tiling, N-edge guarded.
// ---------------------------------------------------------------------------
__global__ void proj_gemm(const float* __restrict__ hs,
                          const float* __restrict__ W_proj,
                          const float* __restrict__ b_proj,
                          float* __restrict__ logits) {
    __shared__ float As[16][65];
    __shared__ float Bs[16][65];
    const int m0 = blockIdx.y * 64;
    const int n0 = blockIdx.x * 64;
    const int tid = threadIdx.x;
    const int tx = tid & 15;
    const int ty = tid >> 4;
    const int lk = tx;
    const int lm = ty;

    const float* arow[4];
    const float* brow[4];
    bool bval[4];
#pragma unroll
    for (int i = 0; i < 4; i++) {
        arow[i] = hs + (size_t)(m0 + lm + i * 16) * HH;
        int n = n0 + lm + i * 16;
        bval[i] = (n < VV);
        brow[i] = W_proj + (size_t)(bval[i] ? n : 0) * HH;
    }

    float acc[4][4] = {};
    for (int k0 = 0; k0 < HH; k0 += 16) {
#pragma unroll
        for (int i = 0; i < 4; i++) As[lk][lm + i * 16] = arow[i][k0 + lk];
#pragma unroll
        for (int i = 0; i < 4; i++)
            Bs[lk][lm + i * 16] = bval[i] ? brow[i][k0 + lk] : 0.f;
        __syncthreads();
#pragma unroll
        for (int k = 0; k < 16; k++) {
            float a[4], bb[4];
#pragma unroll
            for (int i = 0; i < 4; i++) a[i] = As[k][ty + i * 16];
#pragma unroll
            for (int j = 0; j < 4; j++) bb[j] = Bs[k][tx + j * 16];
#pragma unroll
            for (int i = 0; i < 4; i++)
#pragma unroll
                for (int j = 0; j < 4; j++) acc[i][j] += a[i] * bb[j];
        }
        __syncthreads();
    }
#pragma unroll
    for (int i = 0; i < 4; i++) {
        int m = m0 + ty + i * 16;
#pragma unroll
        for (int j = 0; j < 4; j++) {
            int n = n0 + tx + j * 16;
            if (n < VV)
                logits[(size_t)m * VV + n] = acc[i][j] + b_proj[n];
        }
    }
}

// ---------------------------------------------------------------------------
// Kernel D: predictions[bt] = (float)argmax_v logits[bt][v], first-max tiebreak
// ---------------------------------------------------------------------------
__global__ void argmax_kernel(const float* __restrict__ logits,
                              float* __restrict__ preds) {
    const int bt = blockIdx.x;
    const float* row = logits + (size_t)bt * VV;
    const int tid = threadIdx.x;

    float best = -INFINITY;
    int bidx = 0x7fffffff;
    for (int v = tid; v < VV; v += 256) {
        float x = row[v];
        if (x > best) { best = x; bidx = v; }
    }
    __shared__ float sv[256];
    __shared__ int si[256];
    sv[tid] = best;
    si[tid] = bidx;
    __syncthreads();
    for (int s = 128; s > 0; s >>= 1) {
        if (tid < s) {
            float ov = sv[tid + s];
            int oi = si[tid + s];
            if (ov > sv[tid] || (ov == sv[tid] && oi < si[tid])) {
                sv[tid] = ov;
                si[tid] = oi;
            }
        }
        __syncthreads();
    }
    if (tid == 0) preds[bt] = (float)si[0];
}

// ---------------------------------------------------------------------------
extern "C" void kernel_launch(void* const* d_in, const int* in_sizes, int n_in,
                              void* d_out, int out_size, void* d_ws, size_t ws_size,
                              hipStream_t stream) {
    const float* inputs = (const float*)d_in[0];   // [B,H] initial hidden
    const int*   targets = (const int*)d_in[1];    // [B,T]
    const float* emb    = (const float*)d_in[2];   // [V,D]
    const float* W_ih   = (const float*)d_in[3];   // [4H,D]
    const float* W_hh   = (const float*)d_in[4];   // [4H,H]
    const float* b_ih   = (const float*)d_in[5];   // [4H]
    const float* b_hh   = (const float*)d_in[6];   // [4H]
    const float* W_proj = (const float*)d_in[7];   // [V,H]
    const float* b_proj = (const float*)d_in[8];   // [V]

    float* out = (float*)d_out;
    float* logits = out;                             // [B,T,V]
    float* preds = out + (size_t)BB * TT * VV;       // [B,T] as float

    float* ws = (float*)d_ws;
    float* xg = ws;                                  // [B*T, 4H]
    float* hs = xg + (size_t)BB * TT * G4H;          // [B*T, H]
    float* h0 = hs + (size_t)BB * TT * HH;           // [B, H]
    float* h1 = h0 + (size_t)BB * HH;                // [B, H]
    float* cb = h1 + (size_t)BB * HH;                // [B, H]

    // A: input-side gate preactivations for all steps
    xg_gemm<<<dim3(64, 25), 256, 0, stream>>>(targets, emb, W_ih, b_ih, b_hh, xg);

    // B: 50 sequential LSTM steps
    for (int t = 0; t < TT; t++) {
        const float* hp = (t == 0) ? inputs : ((t & 1) ? h0 : h1);
        float* ho = (t & 1) ? h1 : h0;
        lstm_step<<<128, 256, 0, stream>>>(W_hh, xg, hp, cb, ho, hs, t);
    }

    // C: vocab projection
    proj_gemm<<<dim3(786, 25), 256, 0, stream>>>(hs, W_proj, b_proj, logits);

    // D: argmax -> predictions (as float)
    argmax_kernel<<<1600, 256, 0, stream>>>(logits, preds);
}

// Round 4
// 2995.739 us; speedup vs baseline: 1.7793x; 1.7793x over previous
//
#include <hip/hip_runtime.h>
#include <math.h>

#define BB 32
#define TT 50
#define HH 1024
#define DD 512
#define VV 50257
#define G4H 4096

typedef __attribute__((ext_vector_type(8))) short bf16x8;           // 8 bf16 in 4 VGPRs
typedef __attribute__((ext_vector_type(8))) unsigned short u16x8;   // staging vec
typedef __attribute__((ext_vector_type(4))) float f32x4;

__device__ inline unsigned short f2bf(float x) {
    unsigned u = __float_as_uint(x);
    u = (u + 0x7fff + ((u >> 16) & 1)) >> 16;   // RNE
    return (unsigned short)u;
}
__device__ inline float bf2f(unsigned short h) {
    return __uint_as_float(((unsigned)h) << 16);
}

// ---------------------------------------------------------------------------
// split fp32 -> (hi, lo) bf16 pair, vectorized x4
// ---------------------------------------------------------------------------
__global__ void split_f32(const float* __restrict__ x,
                          unsigned short* __restrict__ hi,
                          unsigned short* __restrict__ lo, long n4) {
    long i = (long)blockIdx.x * 256 + threadIdx.x;
    long stride = (long)gridDim.x * 256;
    for (; i < n4; i += stride) {
        float4 v = ((const float4*)x)[i];
        ushort4 h, l;
        h.x = f2bf(v.x); l.x = f2bf(v.x - bf2f(h.x));
        h.y = f2bf(v.y); l.y = f2bf(v.y - bf2f(h.y));
        h.z = f2bf(v.z); l.z = f2bf(v.z - bf2f(h.z));
        h.w = f2bf(v.w); l.w = f2bf(v.w - bf2f(h.w));
        ((ushort4*)hi)[i] = h;
        ((ushort4*)lo)[i] = l;
    }
}

// ---------------------------------------------------------------------------
// Kernel A: xg[bt][n] = dot(emb[tok(bt)], W_ih[n,:]) + b_ih[n] + b_hh[n]
// ---------------------------------------------------------------------------
__global__ void xg_gemm(const int* __restrict__ targets,
                        const float* __restrict__ emb,
                        const float* __restrict__ W_ih,
                        const float* __restrict__ b_ih,
                        const float* __restrict__ b_hh,
                        float* __restrict__ xg) {
    __shared__ float As[16][65];
    __shared__ float Bs[16][65];
    const int m0 = blockIdx.y * 64;
    const int n0 = blockIdx.x * 64;
    const int tid = threadIdx.x;
    const int tx = tid & 15;
    const int ty = tid >> 4;
    const int lk = tx;
    const int lm = ty;

    const float* arow[4];
    const float* brow[4];
#pragma unroll
    for (int i = 0; i < 4; i++) {
        int bt = m0 + lm + i * 16;
        int b = bt / TT, t = bt % TT;
        int tok = (t == 0) ? 1 : targets[b * TT + (t - 1)];
        arow[i] = emb + (size_t)tok * DD;
        int n = n0 + lm + i * 16;
        brow[i] = W_ih + (size_t)n * DD;
    }

    float acc[4][4] = {};
    for (int k0 = 0; k0 < DD; k0 += 16) {
#pragma unroll
        for (int i = 0; i < 4; i++) As[lk][lm + i * 16] = arow[i][k0 + lk];
#pragma unroll
        for (int i = 0; i < 4; i++) Bs[lk][lm + i * 16] = brow[i][k0 + lk];
        __syncthreads();
#pragma unroll
        for (int k = 0; k < 16; k++) {
            float a[4], bb[4];
#pragma unroll
            for (int i = 0; i < 4; i++) a[i] = As[k][ty + i * 16];
#pragma unroll
            for (int j = 0; j < 4; j++) bb[j] = Bs[k][tx + j * 16];
#pragma unroll
            for (int i = 0; i < 4; i++)
#pragma unroll
                for (int j = 0; j < 4; j++) acc[i][j] += a[i] * bb[j];
        }
        __syncthreads();
    }
#pragma unroll
    for (int i = 0; i < 4; i++) {
        int m = m0 + ty + i * 16;
#pragma unroll
        for (int j = 0; j < 4; j++) {
            int n = n0 + tx + j * 16;
            xg[(size_t)m * G4H + n] = acc[i][j] + b_ih[n] + b_hh[n];
        }
    }
}

// ---------------------------------------------------------------------------
// Kernel B: one LSTM time step (unchanged)
// ---------------------------------------------------------------------------
__global__ void lstm_step(const float* __restrict__ W_hh,
                          const float* __restrict__ xg,
                          const float* __restrict__ h_prev,
                          float* __restrict__ c_buf,
                          float* __restrict__ h_out,
                          float* __restrict__ hs_all,
                          int t) {
    __shared__ float h_s[32][65];
    __shared__ float w_s[32][65];
    const int tid = threadIdx.x;
    const int b = tid & 31;
    const int jl = tid >> 5;
    const int n0 = blockIdx.x * 8;
    const int n = n0 + jl;

    float acc[4] = {0.f, 0.f, 0.f, 0.f};
    for (int k0 = 0; k0 < HH; k0 += 64) {
#pragma unroll
        for (int i = 0; i < 8; i++) {
            int e = tid + i * 256;
            int r = e >> 6;
            int kk = e & 63;
            h_s[r][kk] = h_prev[r * HH + k0 + kk];
            int gi = r >> 3, jj = r & 7;
            w_s[r][kk] = W_hh[(size_t)(gi * HH + n0 + jj) * HH + k0 + kk];
        }
        __syncthreads();
#pragma unroll
        for (int k = 0; k < 64; k++) {
            float hv = h_s[b][k];
            acc[0] += hv * w_s[jl][k];
            acc[1] += hv * w_s[8 + jl][k];
            acc[2] += hv * w_s[16 + jl][k];
            acc[3] += hv * w_s[24 + jl][k];
        }
        __syncthreads();
    }

    const int bt = b * TT + t;
    float gi_ = acc[0] + xg[(size_t)bt * G4H + n];
    float gf_ = acc[1] + xg[(size_t)bt * G4H + HH + n];
    float gg_ = acc[2] + xg[(size_t)bt * G4H + 2 * HH + n];
    float go_ = acc[3] + xg[(size_t)bt * G4H + 3 * HH + n];

    float i_ = 1.f / (1.f + expf(-gi_));
    float f_ = 1.f / (1.f + expf(-gf_));
    float g_ = tanhf(gg_);
    float o_ = 1.f / (1.f + expf(-go_));

    float c_old = (t == 0) ? 0.f : c_buf[b * HH + n];
    float c_new = f_ * c_old + i_ * g_;
    float h_new = o_ * tanhf(c_new);

    c_buf[b * HH + n] = c_new;
    h_out[b * HH + n] = h_new;
    hs_all[(size_t)bt * HH + n] = h_new;
}

// ---------------------------------------------------------------------------
// Kernel C: split-bf16 MFMA projection GEMM, REG-STAGED.
// C[m][n] = sum_k (Ah+Al)[m][k]*(Bh+Bl)[n][k], lo*lo dropped.
// 128x128 tile, BK=64, 4 waves (64x64 each), mfma_f32_16x16x32_bf16.
// Staging: thread -> (row = tid>>1, cols (tid&1)*32 .. +32): 32 shorts =
// 4 x u16x8 per array per thread -> full 128x64 tile covered (fixes the
// round-3 half-staged NaN bug). LDS rows padded to 72 shorts: ds_read_b128
// 2-way bank aliased (free), ds_write 4-way.
// ---------------------------------------------------------------------------
#define LROW 72
__global__ __launch_bounds__(256, 2) void proj_mfma(
    const unsigned short* __restrict__ Ah, const unsigned short* __restrict__ Al,
    const unsigned short* __restrict__ Bh, const unsigned short* __restrict__ Bl,
    const float* __restrict__ b_proj, float* __restrict__ logits) {
    __shared__ unsigned short sAh[128 * LROW], sAl[128 * LROW];
    __shared__ unsigned short sBh[128 * LROW], sBl[128 * LROW];
    const int tid = threadIdx.x;
    const int w = tid >> 6;
    const int l = tid & 63;
    const int wr = w >> 1, wc = w & 1;      // wave -> 64x64 quadrant
    const int lr = l & 15, lk = l >> 4;
    const int m0 = blockIdx.y * 128;
    const int n0 = blockIdx.x * 128;

    // staging assignment: thread -> (row = tid>>1, 32-col half = tid&1)
    const int srow = tid >> 1;
    const int sh = (tid & 1) * 32;          // shorts
    int am = m0 + srow; if (am > BB * TT - 1) am = BB * TT - 1;
    int bn = n0 + srow; if (bn > VV - 1) bn = VV - 1;
    const unsigned short* gAh = Ah + (size_t)am * HH + sh;
    const unsigned short* gAl = Al + (size_t)am * HH + sh;
    const unsigned short* gBh = Bh + (size_t)bn * HH + sh;
    const unsigned short* gBl = Bl + (size_t)bn * HH + sh;
    const int wb = srow * LROW + sh;

    u16x8 rA[8], rB[8];   // [0..3]=hi, [4..7]=lo
#define LOADALL(K)                                                  \
    do {                                                            \
        _Pragma("unroll")                                           \
        for (int q = 0; q < 4; q++) {                               \
            rA[q]     = *(const u16x8*)(gAh + (K) + q * 8);         \
            rA[4 + q] = *(const u16x8*)(gAl + (K) + q * 8);         \
            rB[q]     = *(const u16x8*)(gBh + (K) + q * 8);         \
            rB[4 + q] = *(const u16x8*)(gBl + (K) + q * 8);         \
        }                                                           \
    } while (0)

    f32x4 acc[4][4];
#pragma unroll
    for (int i = 0; i < 4; i++)
#pragma unroll
        for (int j = 0; j < 4; j++) acc[i][j] = (f32x4){0.f, 0.f, 0.f, 0.f};

    LOADALL(0);
#pragma unroll 1
    for (int it = 0; it < 16; it++) {
        __syncthreads();                    // previous tile's readers done
#pragma unroll
        for (int q = 0; q < 4; q++) {
            *(u16x8*)&sAh[wb + q * 8] = rA[q];
            *(u16x8*)&sAl[wb + q * 8] = rA[4 + q];
            *(u16x8*)&sBh[wb + q * 8] = rB[q];
            *(u16x8*)&sBl[wb + q * 8] = rB[4 + q];
        }
        const int kn = (it < 15) ? (it + 1) * 64 : 0;   // dummy reload on last
        LOADALL(kn);                        // prefetch next tile; hides under MFMA
        __syncthreads();                    // tile visible

#pragma unroll
        for (int kk = 0; kk < 2; kk++) {
            bf16x8 ah[4], al[4], bh[4], bl[4];
#pragma unroll
            for (int i = 0; i < 4; i++) {
                int ra = (wr * 64 + i * 16 + lr) * LROW + (kk * 4 + lk) * 8;
                ah[i] = *(const bf16x8*)&sAh[ra];
                al[i] = *(const bf16x8*)&sAl[ra];
            }
#pragma unroll
            for (int j = 0; j < 4; j++) {
                int rb = (wc * 64 + j * 16 + lr) * LROW + (kk * 4 + lk) * 8;
                bh[j] = *(const bf16x8*)&sBh[rb];
                bl[j] = *(const bf16x8*)&sBl[rb];
            }
#pragma unroll
            for (int i = 0; i < 4; i++)
#pragma unroll
                for (int j = 0; j < 4; j++) {
                    acc[i][j] = __builtin_amdgcn_mfma_f32_16x16x32_bf16(ah[i], bh[j], acc[i][j], 0, 0, 0);
                    acc[i][j] = __builtin_amdgcn_mfma_f32_16x16x32_bf16(ah[i], bl[j], acc[i][j], 0, 0, 0);
                    acc[i][j] = __builtin_amdgcn_mfma_f32_16x16x32_bf16(al[i], bh[j], acc[i][j], 0, 0, 0);
                }
        }
    }

    // epilogue: C/D layout col(B-idx)=lane&15, row(A-idx)=(lane>>4)*4+reg
#pragma unroll
    for (int j = 0; j < 4; j++) {
        int n = n0 + wc * 64 + j * 16 + lr;
        float bp = b_proj[n < VV ? n : 0];
#pragma unroll
        for (int i = 0; i < 4; i++) {
            int mbase = m0 + wr * 64 + i * 16 + lk * 4;
#pragma unroll
            for (int r = 0; r < 4; r++) {
                int m = mbase + r;
                if (m < BB * TT && n < VV)
                    logits[(size_t)m * VV + n] = acc[i][j][r] + bp;
            }
        }
    }
}

// ---------------------------------------------------------------------------
// Kernel C-fallback: fp32 projection (used only if ws too small)
// ---------------------------------------------------------------------------
__global__ void proj_gemm(const float* __restrict__ hs,
                          const float* __restrict__ W_proj,
                          const float* __restrict__ b_proj,
                          float* __restrict__ logits) {
    __shared__ float As[16][65];
    __shared__ float Bs[16][65];
    const int m0 = blockIdx.y * 64;
    const int n0 = blockIdx.x * 64;
    const int tid = threadIdx.x;
    const int tx = tid & 15;
    const int ty = tid >> 4;
    const int lk = tx;
    const int lm = ty;

    const float* arow[4];
    const float* brow[4];
    bool bval[4];
#pragma unroll
    for (int i = 0; i < 4; i++) {
        arow[i] = hs + (size_t)(m0 + lm + i * 16) * HH;
        int n = n0 + lm + i * 16;
        bval[i] = (n < VV);
        brow[i] = W_proj + (size_t)(bval[i] ? n : 0) * HH;
    }

    float acc[4][4] = {};
    for (int k0 = 0; k0 < HH; k0 += 16) {
#pragma unroll
        for (int i = 0; i < 4; i++) As[lk][lm + i * 16] = arow[i][k0 + lk];
#pragma unroll
        for (int i = 0; i < 4; i++)
            Bs[lk][lm + i * 16] = bval[i] ? brow[i][k0 + lk] : 0.f;
        __syncthreads();
#pragma unroll
        for (int k = 0; k < 16; k++) {
            float a[4], bb[4];
#pragma unroll
            for (int i = 0; i < 4; i++) a[i] = As[k][ty + i * 16];
#pragma unroll
            for (int j = 0; j < 4; j++) bb[j] = Bs[k][tx + j * 16];
#pragma unroll
            for (int i = 0; i < 4; i++)
#pragma unroll
                for (int j = 0; j < 4; j++) acc[i][j] += a[i] * bb[j];
        }
        __syncthreads();
    }
#pragma unroll
    for (int i = 0; i < 4; i++) {
        int m = m0 + ty + i * 16;
#pragma unroll
        for (int j = 0; j < 4; j++) {
            int n = n0 + tx + j * 16;
            if (n < VV)
                logits[(size_t)m * VV + n] = acc[i][j] + b_proj[n];
        }
    }
}

// ---------------------------------------------------------------------------
// Kernel D: argmax
// ---------------------------------------------------------------------------
__global__ void argmax_kernel(const float* __restrict__ logits,
                              float* __restrict__ preds) {
    const int bt = blockIdx.x;
    const float* row = logits + (size_t)bt * VV;
    const int tid = threadIdx.x;

    float best = -INFINITY;
    int bidx = 0x7fffffff;
    for (int v = tid; v < VV; v += 256) {
        float x = row[v];
        if (x > best) { best = x; bidx = v; }
    }
    __shared__ float sv[256];
    __shared__ int si[256];
    sv[tid] = best;
    si[tid] = bidx;
    __syncthreads();
    for (int s = 128; s > 0; s >>= 1) {
        if (tid < s) {
            float ov = sv[tid + s];
            int oi = si[tid + s];
            if (ov > sv[tid] || (ov == sv[tid] && oi < si[tid])) {
                sv[tid] = ov;
                si[tid] = oi;
            }
        }
        __syncthreads();
    }
    if (tid == 0) preds[bt] = (float)si[0];
}

// ---------------------------------------------------------------------------
extern "C" void kernel_launch(void* const* d_in, const int* in_sizes, int n_in,
                              void* d_out, int out_size, void* d_ws, size_t ws_size,
                              hipStream_t stream) {
    const float* inputs = (const float*)d_in[0];
    const int*   targets = (const int*)d_in[1];
    const float* emb    = (const float*)d_in[2];
    const float* W_ih   = (const float*)d_in[3];
    const float* W_hh   = (const float*)d_in[4];
    const float* b_ih   = (const float*)d_in[5];
    const float* b_hh   = (const float*)d_in[6];
    const float* W_proj = (const float*)d_in[7];
    const float* b_proj = (const float*)d_in[8];

    float* out = (float*)d_out;
    float* logits = out;
    float* preds = out + (size_t)BB * TT * VV;

    float* ws = (float*)d_ws;
    float* xg = ws;                                  // [B*T,4H]
    float* hs = xg + (size_t)BB * TT * G4H;          // [B*T,H]
    float* h0 = hs + (size_t)BB * TT * HH;
    float* h1 = h0 + (size_t)BB * HH;
    float* cb = h1 + (size_t)BB * HH;
    unsigned short* Ah = (unsigned short*)(cb + (size_t)BB * HH);
    unsigned short* Al = Ah + (size_t)BB * TT * HH;
    unsigned short* Bh = Al + (size_t)BB * TT * HH;
    unsigned short* Bl = Bh + (size_t)VV * HH;

    size_t need = ((size_t)BB * TT * G4H + (size_t)BB * TT * HH + 3 * (size_t)BB * HH) * 4
                + ((size_t)2 * BB * TT * HH + (size_t)2 * VV * HH) * 2;
    bool fast = (ws_size >= need);

    if (fast) {
        split_f32<<<4096, 256, 0, stream>>>(W_proj, Bh, Bl, (long)VV * HH / 4);
    }

    xg_gemm<<<dim3(64, 25), 256, 0, stream>>>(targets, emb, W_ih, b_ih, b_hh, xg);

    for (int t = 0; t < TT; t++) {
        const float* hp = (t == 0) ? inputs : ((t & 1) ? h0 : h1);
        float* ho = (t & 1) ? h1 : h0;
        lstm_step<<<128, 256, 0, stream>>>(W_hh, xg, hp, cb, ho, hs, t);
    }

    if (fast) {
        split_f32<<<1600, 256, 0, stream>>>(hs, Ah, Al, (long)BB * TT * HH / 4);
        proj_mfma<<<dim3(393, 13), 256, 0, stream>>>(Ah, Al, Bh, Bl, b_proj, logits);
    } else {
        proj_gemm<<<dim3(786, 25), 256, 0, stream>>>(hs, W_proj, b_proj, logits);
    }

    argmax_kernel<<<1600, 256, 0, stream>>>(logits, preds);
}